// Round 12
// baseline (211.875 us; speedup 1.0000x reference)
//
#include <hip/hip_runtime.h>

#define Bq 8
#define Tq 64
#define Sq 256
#define Hq 768
#define GPB 16          // workgroups per batch (scan)
#define NSTEP 64

typedef float f32x4 __attribute__((ext_vector_type(4)));
typedef __bf16 bf16x8 __attribute__((ext_vector_type(8)));

#define TANH_SCALE 2.885390081777927f   // 2*log2(e)
#define INV_TS     0.34657359027997264f // 1/TANH_SCALE
#define LOG2E 1.4426950408889634f
#define POISON 0xFFFFFFFFu

// packed sync word: [63:58]=count, [57:32]=P*2^12, [31:0]=Q*2^14 + 2^26/adder
#define CNT_ONE (1ULL << 58)
#define P_SCALE 4096.0f
#define Q_SCALE 16384.0f
#define Q_BIAS  67108864.0f            // 2^26 per adder
#define Q_BIAS_TOT (16.0f * 67108864.0f)

// ---- DPP reduction helpers ---------------------------------------------------
template <int Ctrl, int Rmask>
__device__ __forceinline__ float dpp_add_f(float v) {
  int t = __builtin_amdgcn_update_dpp(0, __float_as_int(v), Ctrl, Rmask, 0xF, true);
  return v + __int_as_float(t);
}
__device__ __forceinline__ float wave64_sum(float v) {
  v = dpp_add_f<0xB1, 0xF>(v);
  v = dpp_add_f<0x4E, 0xF>(v);
  v = dpp_add_f<0x141, 0xF>(v);
  v = dpp_add_f<0x140, 0xF>(v);
  v = dpp_add_f<0x142, 0xA>(v);
  v = dpp_add_f<0x143, 0xC>(v);
  return __int_as_float(__builtin_amdgcn_readlane(__float_as_int(v), 63));
}
// per-16-lane-row sum (row0 and row1 reduce independently)
__device__ __forceinline__ float row16_sum(float v) {
  v = dpp_add_f<0xB1, 0xF>(v);
  v = dpp_add_f<0x4E, 0xF>(v);
  v = dpp_add_f<0x141, 0xF>(v);
  v = dpp_add_f<0x140, 0xF>(v);
  return v;
}

// ---------------- projection GEMMs (bf16 MFMA) --------------------------------
__global__ __launch_bounds__(256) void proj_kernel(
    const float* __restrict__ enc, const float* __restrict__ dec,
    const float* __restrict__ Wh, const float* __restrict__ Wd,
    const float* __restrict__ bd,
    float* __restrict__ ef, float* __restrict__ decf,
    unsigned long long* __restrict__ Zsync, float* __restrict__ lacc)
{
  {
    int idx = blockIdx.x * 256 + threadIdx.x;
    if (idx < Bq * NSTEP * 8) Zsync[idx] = 0ULL;
    if (idx == 0) lacc[0] = 0.f;
  }

  int bid = blockIdx.x;
  const int efBlocks = 384;
  const float* A; const float* W; float* C; bool hasBias;
  int bm, bn;
  if (bid < efBlocks) {
    A = enc; W = Wh; C = ef; hasBias = false;
    bm = bid % 32; bn = bid / 32;
  } else {
    bid -= efBlocks;
    A = dec; W = Wd; C = decf; hasBias = true;
    bm = bid % 8; bn = bid / 8;
  }
  int w = threadIdx.x >> 6, ln = threadIdx.x & 63;
  int m0 = bm * 64 + (w >> 1) * 32;
  int n0 = bn * 64 + (w & 1) * 32;
  int rsel = ln & 15;
  int kof = (ln >> 4) * 8;
  f32x4 acc[2][2] = {};
  for (int k0 = 0; k0 < Hq; k0 += 32) {
    bf16x8 af[2], bfr[2];
#pragma unroll
    for (int tm = 0; tm < 2; tm++) {
      const float* p = A + (size_t)(m0 + tm * 16 + rsel) * Hq + k0 + kof;
      f32x4 lo = *(const f32x4*)p, hi = *(const f32x4*)(p + 4);
      bf16x8 t;
      t[0] = (__bf16)lo[0]; t[1] = (__bf16)lo[1]; t[2] = (__bf16)lo[2]; t[3] = (__bf16)lo[3];
      t[4] = (__bf16)hi[0]; t[5] = (__bf16)hi[1]; t[6] = (__bf16)hi[2]; t[7] = (__bf16)hi[3];
      af[tm] = t;
    }
#pragma unroll
    for (int tn = 0; tn < 2; tn++) {
      const float* p = W + (size_t)(n0 + tn * 16 + rsel) * Hq + k0 + kof;
      f32x4 lo = *(const f32x4*)p, hi = *(const f32x4*)(p + 4);
      bf16x8 t;
      t[0] = (__bf16)lo[0]; t[1] = (__bf16)lo[1]; t[2] = (__bf16)lo[2]; t[3] = (__bf16)lo[3];
      t[4] = (__bf16)hi[0]; t[5] = (__bf16)hi[1]; t[6] = (__bf16)hi[2]; t[7] = (__bf16)hi[3];
      bfr[tn] = t;
    }
#pragma unroll
    for (int tm = 0; tm < 2; tm++)
#pragma unroll
      for (int tn = 0; tn < 2; tn++)
        acc[tm][tn] = __builtin_amdgcn_mfma_f32_16x16x32_bf16(af[tm], bfr[tn], acc[tm][tn], 0, 0, 0);
  }
  int col = ln & 15, rb = (ln >> 4) * 4;
#pragma unroll
  for (int tm = 0; tm < 2; tm++)
#pragma unroll
    for (int tn = 0; tn < 2; tn++)
#pragma unroll
      for (int j = 0; j < 4; j++) {
        int r = m0 + tm * 16 + rb + j, c = n0 + tn * 16 + col;
        float val = acc[tm][tn][j];
        if (hasBias) val += bd[c];
        C[(size_t)r * Hq + c] = val * TANH_SCALE;
      }
}

// ---------------- persistent scan kernel (2-step-ahead P,Q pipeline) ----------
// 128 blocks x 1024 threads (16 waves, 1 row/wave). During iteration t each WG
// posts word_{t+2}: P = sum exp(A at base cov_{t+1}), Q = sum exp(A)*E_{t+1}*
// INV_TS*B, so word_{t+1} is already full when read: Z_{t+1} = P + invZ_t * Q.
// The IC add/travel drops off the per-step critical path.
__global__ __launch_bounds__(1024, 1) void scan_kernel(
    const float* __restrict__ ef, const float* __restrict__ decf,
    const float* __restrict__ emask, const float* __restrict__ cov0,
    const float* __restrict__ vvec, const float* __restrict__ wcvec,
    const float* __restrict__ dmask,
    float* __restrict__ out_attn, float* __restrict__ out_covf,
    unsigned long long* __restrict__ Zsync, float* __restrict__ lacc)
{
  __shared__ unsigned zsP[NSTEP][16];    // write-once per t: per-wave exp(A) part
  __shared__ unsigned zsQ[NSTEP][16];    // write-once per t: per-wave Q part
  __shared__ unsigned zshs[NSTEP];       // write-once Z relay
  __shared__ float lossb[16];
  const int b = blockIdx.x & 7;
  const int g = blockIdx.x >> 3;
  const int w = threadIdx.x >> 6;        // 0..15
  const int ln = threadIdx.x & 63;
  const int tid = threadIdx.x;
  const int s0 = g * 16 + w;
  const int hb = 4 * ln;

  ((unsigned*)zsP)[tid] = POISON;
  ((unsigned*)zsQ)[tid] = POISON;
  if (tid < NSTEP) zshs[tid] = POISON;
  __syncthreads();

  f32x4 vv[3], wcv[3], vwc4[3], ef0[3];
  const float* efr0 = ef + (size_t)(b * Sq + s0) * Hq;
#pragma unroll
  for (int jj = 0; jj < 3; jj++) {
    int o = hb + 256 * jj;
    vv[jj]  = *(const f32x4*)(vvec + o);
    f32x4 wcl = *(const f32x4*)(wcvec + o);
    wcv[jj] = wcl * TANH_SCALE;
    vwc4[jj] = vv[jj] * wcv[jj] * 4.0f;
    ef0[jj] = *(const f32x4*)(efr0 + o);
  }
  float cva = cov0[b * Sq + s0];
  const float em0 = emask[b * Sq + s0];
  const float dm = dmask[b * Tq + ln];
  float lkeep = 0.f;

  const float* decb = decf + (size_t)(b * Tq) * Hq;
  unsigned long long* Zw = Zsync + (size_t)(b * NSTEP) * 8;

  // ---- prologue -------------------------------------------------------------
  f32x4 dvn[3];
  // step 0: exact E_0 at cov_0; word_0 = (P=sum E_0, Q=0)
#pragma unroll
  for (int jj = 0; jj < 3; jj++) dvn[jj] = *(const f32x4*)(decb + hb + 256 * jj);
  float E;
  {
    float accA = 0.f;
#pragma unroll
    for (int jj = 0; jj < 3; jj++)
#pragma unroll
      for (int e = 0; e < 4; e++) {
        float xa = ef0[jj][e] + dvn[jj][e] + cva * wcv[jj][e];
        float ta = 1.f - 2.f * __builtin_amdgcn_rcpf(1.f + __builtin_amdgcn_exp2f(xa));
        accA += vv[jj][e] * ta;
      }
    float A0 = wave64_sum(accA);
    E = __builtin_amdgcn_exp2f(A0 * LOG2E) * em0;
  }
  if (ln == 0) {
    __hip_atomic_store(&zsP[0][w], __float_as_uint(E), __ATOMIC_RELAXED, __HIP_MEMORY_SCOPE_WORKGROUP);
    __hip_atomic_store(&zsQ[0][w], __float_as_uint(0.f), __ATOMIC_RELAXED, __HIP_MEMORY_SCOPE_WORKGROUP);
  }
  // spec for step 1 at base cov_0
  float An, Bn;
#pragma unroll
  for (int jj = 0; jj < 3; jj++) dvn[jj] = *(const f32x4*)(decb + Hq + hb + 256 * jj);
  {
    float accA = 0.f, accB = 0.f;
#pragma unroll
    for (int jj = 0; jj < 3; jj++)
#pragma unroll
      for (int e = 0; e < 4; e++) {
        float xa = ef0[jj][e] + dvn[jj][e] + cva * wcv[jj][e];
        float r  = __builtin_amdgcn_rcpf(1.f + __builtin_amdgcn_exp2f(xa));
        accA += vv[jj][e] * (1.f - 2.f * r);
        accB += vwc4[jj][e] * (r - r * r);
      }
    An = wave64_sum(accA);
    Bn = wave64_sum(accB);
  }
  {
    float eA = __builtin_amdgcn_exp2f(An * LOG2E) * em0;
    float q  = eA * E * INV_TS * Bn;
    if (ln == 0) {
      __hip_atomic_store(&zsP[1][w], __float_as_uint(eA), __ATOMIC_RELAXED, __HIP_MEMORY_SCOPE_WORKGROUP);
      __hip_atomic_store(&zsQ[1][w], __float_as_uint(q), __ATOMIC_RELAXED, __HIP_MEMORY_SCOPE_WORKGROUP);
    }
  }
  // wave0: gather+post word_0 and word_1
  if (w == 0) {
#pragma unroll
    for (int widx = 0; widx < 2; widx++) {
      unsigned raw = 0;
      do {
        if (ln < 16)       raw = __hip_atomic_load(&zsP[widx][ln], __ATOMIC_RELAXED, __HIP_MEMORY_SCOPE_WORKGROUP);
        else if (ln < 32)  raw = __hip_atomic_load(&zsQ[widx][ln - 16], __ATOMIC_RELAXED, __HIP_MEMORY_SCOPE_WORKGROUP);
      } while (__ballot(raw == POISON));
      float val = row16_sum(__uint_as_float(raw));
      float Ps = __shfl(val, 0), Qs = __shfl(val, 16);
      if (ln == 0) {
        Ps = fminf(Ps, 1008.f);
        Qs = fminf(fmaxf(Qs, -4000.f), 4000.f);
        unsigned long long pkt = CNT_ONE
          | ((unsigned long long)(unsigned)(Ps * P_SCALE + 0.5f) << 32)
          | (unsigned long long)(unsigned)(Qs * Q_SCALE + Q_BIAS + 0.5f);
        atomicAdd(&Zw[widx * 8], pkt);
      }
    }
  }
  // preload dec row 2 for iteration 0's spec (step 2)
#pragma unroll
  for (int jj = 0; jj < 3; jj++) dvn[jj] = *(const f32x4*)(decb + 2 * Hq + hb + 256 * jj);

  float invZprev = 0.f;
  unsigned long long pend = __hip_atomic_load(&Zw[0], __ATOMIC_RELAXED, __HIP_MEMORY_SCOPE_AGENT);

  // ---- main loop ------------------------------------------------------------
  for (int t = 0; t < NSTEP; t++) {
    // acquire Z_t
    float zf;
    if (w == 0) {
      unsigned long long v = pend;
      while ((unsigned)(v >> 58) != GPB)
        v = __hip_atomic_load(&Zw[t * 8], __ATOMIC_RELAXED, __HIP_MEMORY_SCOPE_AGENT);
      float P = (float)((unsigned)((v >> 32) & 0x3FFFFFFu)) * (1.0f / P_SCALE);
      float Q = ((float)((unsigned)v) - Q_BIAS_TOT) * (1.0f / Q_SCALE);
      zf = P + invZprev * Q;
      __hip_atomic_store(&zshs[t], __float_as_uint(zf), __ATOMIC_RELAXED, __HIP_MEMORY_SCOPE_WORKGROUP);
    } else {
      unsigned u;
      do {
        u = __hip_atomic_load(&zshs[t], __ATOMIC_RELAXED, __HIP_MEMORY_SCOPE_WORKGROUP);
      } while (u == POISON);
      zf = __uint_as_float(u);
    }

    const float invZ = __builtin_amdgcn_rcpf(zf);
    float at0 = E * invZ;
    float lterm = fminf(at0, cva);
    lkeep = (ln == t) ? lterm : lkeep;
    cva += at0;
    if (ln == 0)
      out_attn[(size_t)(b * Tq + t) * Sq + s0] = at0;
    invZprev = invZ;

    // pre-issue next word load early (value checked next iteration)
    if (w == 0 && t + 1 < NSTEP)
      pend = __hip_atomic_load(&Zw[(t + 1) * 8], __ATOMIC_RELAXED, __HIP_MEMORY_SCOPE_AGENT);

    // per-row E_{t+1} via exponent-Taylor at base cov_t
    if (t + 1 < NSTEP)
      E = __builtin_amdgcn_exp2f((An + at0 * INV_TS * Bn) * LOG2E) * em0;

    // spec for step t+2 at (exact) base cov_{t+1}; post word_{t+2}
    if (t + 2 < NSTEP) {
      f32x4 dvf[3];
      if (t + 3 < NSTEP) {
        const float* drn = decb + (size_t)(t + 3) * Hq;
#pragma unroll
        for (int jj = 0; jj < 3; jj++) dvf[jj] = *(const f32x4*)(drn + hb + 256 * jj);
      }
      float accA = 0.f, accB = 0.f;
#pragma unroll
      for (int jj = 0; jj < 3; jj++)
#pragma unroll
        for (int e = 0; e < 4; e++) {
          float xa = ef0[jj][e] + dvn[jj][e] + cva * wcv[jj][e];
          float r  = __builtin_amdgcn_rcpf(1.f + __builtin_amdgcn_exp2f(xa));
          accA += vv[jj][e] * (1.f - 2.f * r);
          accB += vwc4[jj][e] * (r - r * r);
        }
      float A2 = wave64_sum(accA);
      float B2 = wave64_sum(accB);
      float eA = __builtin_amdgcn_exp2f(A2 * LOG2E) * em0;
      float q  = eA * E * INV_TS * B2;
      if (ln == 0) {
        __hip_atomic_store(&zsP[t + 2][w], __float_as_uint(eA), __ATOMIC_RELAXED, __HIP_MEMORY_SCOPE_WORKGROUP);
        __hip_atomic_store(&zsQ[t + 2][w], __float_as_uint(q), __ATOMIC_RELAXED, __HIP_MEMORY_SCOPE_WORKGROUP);
      }
      An = A2; Bn = B2;
#pragma unroll
      for (int jj = 0; jj < 3; jj++) dvn[jj] = dvf[jj];

      if (w == 0) {
        unsigned raw = 0;
        do {
          if (ln < 16)      raw = __hip_atomic_load(&zsP[t + 2][ln], __ATOMIC_RELAXED, __HIP_MEMORY_SCOPE_WORKGROUP);
          else if (ln < 32) raw = __hip_atomic_load(&zsQ[t + 2][ln - 16], __ATOMIC_RELAXED, __HIP_MEMORY_SCOPE_WORKGROUP);
        } while (__ballot(raw == POISON));
        float val = row16_sum(__uint_as_float(raw));
        float Ps = __shfl(val, 0), Qs = __shfl(val, 16);
        if (ln == 0) {
          Ps = fminf(Ps, 1008.f);
          Qs = fminf(fmaxf(Qs, -4000.f), 4000.f);
          unsigned long long pkt = CNT_ONE
            | ((unsigned long long)(unsigned)(Ps * P_SCALE + 0.5f) << 32)
            | (unsigned long long)(unsigned)(Qs * Q_SCALE + Q_BIAS + 0.5f);
          atomicAdd(&Zw[(t + 2) * 8], pkt);
        }
      }
    }
  }

  float lp = wave64_sum(lkeep * dm);
  if (ln == 0) {
    out_covf[b * Sq + s0] = cva;
    lossb[w] = lp;
  }
  __syncthreads();
  if (w == 0) {
    float p = (ln < 16) ? lossb[ln] : 0.f;
    p += __shfl_xor(p, 1); p += __shfl_xor(p, 2);
    p += __shfl_xor(p, 4); p += __shfl_xor(p, 8);
    if (ln == 0) atomicAdd(lacc, p);
  }
}

// ---------------- deferred ht = attn @ enc + loss finalize --------------------
__global__ __launch_bounds__(256) void ht_kernel(
    const float* __restrict__ attn, const float* __restrict__ enc,
    const float* __restrict__ dmask, const float* __restrict__ lacc,
    float* __restrict__ out_ht, float* __restrict__ out_loss)
{
  __shared__ float lat[Sq][8];
  __shared__ float r4[4];
  int bid = blockIdx.x;
  int b = bid / 24, r = bid % 24, tc = r / 3, hc = r % 3;
  int tid = threadIdx.x;
  int h = hc * 256 + tid;
#pragma unroll
  for (int tt = 0; tt < 8; tt++)
    lat[tid][tt] = attn[(size_t)(b * Tq + tc * 8 + tt) * Sq + tid];
  __syncthreads();

  float acc[8] = {};
  const float* ep = enc + (size_t)(b * Sq) * Hq + h;
  for (int sb = 0; sb < Sq; sb += 8) {
    float e[8];
#pragma unroll
    for (int u = 0; u < 8; u++) e[u] = ep[(size_t)(sb + u) * Hq];
#pragma unroll
    for (int u = 0; u < 8; u++) {
      f32x4 a0 = *(const f32x4*)&lat[sb + u][0];
      f32x4 a1 = *(const f32x4*)&lat[sb + u][4];
      acc[0] += a0[0] * e[u]; acc[1] += a0[1] * e[u];
      acc[2] += a0[2] * e[u]; acc[3] += a0[3] * e[u];
      acc[4] += a1[0] * e[u]; acc[5] += a1[1] * e[u];
      acc[6] += a1[2] * e[u]; acc[7] += a1[3] * e[u];
    }
  }
#pragma unroll
  for (int tt = 0; tt < 8; tt++)
    out_ht[(size_t)(b * Tq + tc * 8 + tt) * Hq + h] = acc[tt];

  if (blockIdx.x == 0) {
    float s = 0.f;
    for (int i = tid; i < Bq * Tq; i += 256) s += dmask[i];
#pragma unroll
    for (int off = 32; off; off >>= 1) s += __shfl_xor(s, off);
    int w = tid >> 6, ln = tid & 63;
    if (ln == 0) r4[w] = s;
    __syncthreads();
    if (tid == 0) out_loss[0] = lacc[0] / (r4[0] + r4[1] + r4[2] + r4[3]);
  }
}

extern "C" void kernel_launch(void* const* d_in, const int* in_sizes, int n_in,
                              void* d_out, int out_size, void* d_ws, size_t ws_size,
                              hipStream_t stream) {
  const float* dec   = (const float*)d_in[0];
  const float* dmask = (const float*)d_in[1];
  const float* enc   = (const float*)d_in[2];
  const float* emask = (const float*)d_in[3];
  const float* cov0  = (const float*)d_in[4];
  const float* Wh    = (const float*)d_in[5];
  const float* Wd    = (const float*)d_in[6];
  const float* bd    = (const float*)d_in[7];
  const float* wc    = (const float*)d_in[8];
  const float* vv    = (const float*)d_in[9];
  float* out = (float*)d_out;

  char* ws = (char*)d_ws;
  float* ef   = (float*)ws;                           // 6291456 B
  float* decf = (float*)(ws + 6291456);               // 1572864 B
  unsigned long long* Zsync = (unsigned long long*)(ws + 7864320); // 32768 B
  float* lacc = (float*)(ws + 7897088);               // 4 B

  const size_t OFF_ATTN = (size_t)Bq * Tq * Hq;             // 393216
  const size_t OFF_LOSS = OFF_ATTN + (size_t)Bq * Tq * Sq;  // 524288
  const size_t OFF_COV  = OFF_LOSS + 1;                     // 524289

  proj_kernel<<<480, 256, 0, stream>>>(enc, dec, Wh, Wd, bd, ef, decf,
                                       Zsync, lacc);
  scan_kernel<<<Bq * GPB, 1024, 0, stream>>>(ef, decf, emask, cov0, vv, wc,
                                             dmask, out + OFF_ATTN,
                                             out + OFF_COV, Zsync, lacc);
  ht_kernel<<<192, 256, 0, stream>>>(out + OFF_ATTN, enc, dmask, lacc,
                                     out, out + OFF_LOSS);
}

// Round 13
// 161.928 us; speedup vs baseline: 1.3084x; 1.3084x over previous
//
#include <hip/hip_runtime.h>

#define Bq 8
#define Tq 64
#define Sq 256
#define Hq 768

typedef float f32x4 __attribute__((ext_vector_type(4)));
typedef __bf16 bf16x8 __attribute__((ext_vector_type(8)));

#define TANH_SCALE 2.885390081777927f   // 2*log2(e): exp2(u*TS) = e^{2u}
#define LOG2E 1.4426950408889634f

// ---- DPP wave reduction -----------------------------------------------------
template <int Ctrl, int Rmask>
__device__ __forceinline__ float dpp_add_f(float v) {
  int t = __builtin_amdgcn_update_dpp(0, __float_as_int(v), Ctrl, Rmask, 0xF, true);
  return v + __int_as_float(t);
}
__device__ __forceinline__ float wave64_sum(float v) {
  v = dpp_add_f<0xB1, 0xF>(v);
  v = dpp_add_f<0x4E, 0xF>(v);
  v = dpp_add_f<0x141, 0xF>(v);
  v = dpp_add_f<0x140, 0xF>(v);
  v = dpp_add_f<0x142, 0xA>(v);
  v = dpp_add_f<0x143, 0xC>(v);
  return __int_as_float(__builtin_amdgcn_readlane(__float_as_int(v), 63));
}

// ---------------- projection GEMMs (bf16 MFMA) --------------------------------
// ef output stored as bf16 (TS-scaled); decf stays f32 (TS-scaled, +bias).
__global__ __launch_bounds__(256) void proj_kernel(
    const float* __restrict__ enc, const float* __restrict__ dec,
    const float* __restrict__ Wh, const float* __restrict__ Wd,
    const float* __restrict__ bd,
    __bf16* __restrict__ efh, float* __restrict__ decf,
    float* __restrict__ lacc)
{
  if (blockIdx.x == 0 && threadIdx.x == 0) lacc[0] = 0.f;

  int bid = blockIdx.x;
  const int efBlocks = 384;
  const float* A; const float* W; bool isEf;
  int bm, bn;
  if (bid < efBlocks) {
    A = enc; W = Wh; isEf = true;
    bm = bid % 32; bn = bid / 32;               // XCD affinity: bm%8 = bid%8
  } else {
    bid -= efBlocks;
    A = dec; W = Wd; isEf = false;
    bm = bid % 8; bn = bid / 8;
  }
  int w = threadIdx.x >> 6, ln = threadIdx.x & 63;
  int m0 = bm * 64 + (w >> 1) * 32;
  int n0 = bn * 64 + (w & 1) * 32;
  int rsel = ln & 15;
  int kof = (ln >> 4) * 8;
  f32x4 acc[2][2] = {};
  for (int k0 = 0; k0 < Hq; k0 += 32) {
    bf16x8 af[2], bfr[2];
#pragma unroll
    for (int tm = 0; tm < 2; tm++) {
      const float* p = A + (size_t)(m0 + tm * 16 + rsel) * Hq + k0 + kof;
      f32x4 lo = *(const f32x4*)p, hi = *(const f32x4*)(p + 4);
      bf16x8 t;
      t[0] = (__bf16)lo[0]; t[1] = (__bf16)lo[1]; t[2] = (__bf16)lo[2]; t[3] = (__bf16)lo[3];
      t[4] = (__bf16)hi[0]; t[5] = (__bf16)hi[1]; t[6] = (__bf16)hi[2]; t[7] = (__bf16)hi[3];
      af[tm] = t;
    }
#pragma unroll
    for (int tn = 0; tn < 2; tn++) {
      const float* p = W + (size_t)(n0 + tn * 16 + rsel) * Hq + k0 + kof;
      f32x4 lo = *(const f32x4*)p, hi = *(const f32x4*)(p + 4);
      bf16x8 t;
      t[0] = (__bf16)lo[0]; t[1] = (__bf16)lo[1]; t[2] = (__bf16)lo[2]; t[3] = (__bf16)lo[3];
      t[4] = (__bf16)hi[0]; t[5] = (__bf16)hi[1]; t[6] = (__bf16)hi[2]; t[7] = (__bf16)hi[3];
      bfr[tn] = t;
    }
#pragma unroll
    for (int tm = 0; tm < 2; tm++)
#pragma unroll
      for (int tn = 0; tn < 2; tn++)
        acc[tm][tn] = __builtin_amdgcn_mfma_f32_16x16x32_bf16(af[tm], bfr[tn], acc[tm][tn], 0, 0, 0);
  }
  int col = ln & 15, rb = (ln >> 4) * 4;
#pragma unroll
  for (int tm = 0; tm < 2; tm++)
#pragma unroll
    for (int tn = 0; tn < 2; tn++)
#pragma unroll
      for (int j = 0; j < 4; j++) {
        int r = m0 + tm * 16 + rb + j, c = n0 + tn * 16 + col;
        float val = acc[tm][tn][j];
        if (isEf) {
          efh[(size_t)r * Hq + c] = (__bf16)(val * TANH_SCALE);
        } else {
          decf[(size_t)r * Hq + c] = (val + bd[c]) * TANH_SCALE;
        }
      }
}

// ---------------- ABCD precompute ---------------------------------------------
// score_s(t; cov) ~= A + cov*B + cov^2*C + cov^3*D (Taylor of sum_h v*tanh at
// cov=0; exact u0 = ef_s + dec_t). Thread = one (t,s) pair, h serial from LDS.
// 512 blocks = 8b x (4 t-tiles x 16 s-tiles); b = bid&7 -> XCD-affine with scan2.
#define TT 16
#define ST 16
__global__ __launch_bounds__(256, 2) void abcd_kernel(
    const __bf16* __restrict__ efh, const float* __restrict__ decf,
    const float* __restrict__ wcvec, const float* __restrict__ vvec,
    f32x4* __restrict__ abcd)
{
  __shared__ unsigned short efs[ST][772];   // bf16 bits, pad 772 (bank-clean)
  __shared__ float dts[TT][772];
  __shared__ float wcs[768], vvs[768];
  const int b = blockIdx.x & 7;
  const int r = blockIdx.x >> 3;            // 0..63
  const int tt0 = (r & 3) * TT;
  const int st0 = (r >> 2) * ST;
  const int tid = threadIdx.x;

  // stage ef tile (uint = 2 bf16), dec tile (f32x4), v/wc
  for (int i = tid; i < ST * 384; i += 256) {
    int row = i / 384, c2 = (i % 384) * 2;
    *(unsigned*)&efs[row][c2] =
        *(const unsigned*)(efh + (size_t)(b * Sq + st0 + row) * Hq + c2);
  }
  for (int i = tid; i < TT * 192; i += 256) {
    int row = i / 192, c4 = (i % 192) * 4;
    *(f32x4*)&dts[row][c4] =
        *(const f32x4*)(decf + (size_t)(b * Tq + tt0 + row) * Hq + c4);
  }
  for (int i = tid; i < 768; i += 256) { wcs[i] = wcvec[i]; vvs[i] = vvec[i]; }
  __syncthreads();

  const int tl = tid >> 4, sl = tid & 15;
  float A = 0.f, Bc = 0.f, Cc = 0.f, Dc = 0.f;
#pragma unroll 4
  for (int h = 0; h < 768; h++) {
    float u = __uint_as_float((unsigned)efs[sl][h] << 16) + dts[tl][h]; // TS-scaled
    float e2 = __builtin_amdgcn_exp2f(u);
    float rr = __builtin_amdgcn_rcpf(1.f + e2);
    float t0 = 1.f - 2.f * rr;              // tanh(u0)
    float f1 = 1.f - t0 * t0;               // tanh'
    float wc = wcs[h], vx = vvs[h];
    float vwc = vx * wc;
    A  += vx * t0;
    Bc += vwc * f1;
    Cc -= vwc * wc * t0 * f1;               // (1/2) v wc^2 f'' = -v wc^2 t f1
    Dc += vwc * wc * wc * f1 * (t0 * t0 - (1.f / 3.f)); // (1/6) v wc^3 f'''
  }
  f32x4 outv; outv[0] = A; outv[1] = Bc; outv[2] = Cc; outv[3] = Dc;
  abcd[(size_t)(b * Tq + tt0 + tl) * Sq + st0 + sl] = outv;
}

// ---------------- scan: one batch = one 256-thread block ----------------------
// Thread s owns row s. Per step: cubic poly in cov + exp + intra-block Z
// reduction (DPP + 4-slot LDS). NO cross-WG sync. ~0.15us/step.
__global__ __launch_bounds__(256, 1) void scan2_kernel(
    const f32x4* __restrict__ abcd, const float* __restrict__ emask,
    const float* __restrict__ cov0, const float* __restrict__ dmask,
    float* __restrict__ out_attn, float* __restrict__ out_covf,
    float* __restrict__ lacc)
{
  __shared__ float zp[2][4];
  __shared__ float dms[Tq];
  __shared__ float lred[4];
  const int b = blockIdx.x;
  const int s = threadIdx.x;
  const int w = s >> 6, ln = s & 63;
  if (s < Tq) dms[s] = dmask[b * Tq + s];
  const float em = emask[b * Sq + s];
  float cov = cov0[b * Sq + s];
  float lp = 0.f;
  const f32x4* P = abcd + (size_t)b * Tq * Sq + s;
  f32x4 cur = P[0];
  __syncthreads();

  for (int t = 0; t < Tq; t++) {
    f32x4 nxt = (t + 1 < Tq) ? P[(size_t)(t + 1) * Sq] : cur;  // prefetch
    float sc = cur[0] + cov * (cur[1] + cov * (cur[2] + cov * cur[3]));
    float E = __builtin_amdgcn_exp2f(sc * LOG2E) * em;
    float wsum = wave64_sum(E);
    if (ln == 0) zp[t & 1][w] = wsum;
    __syncthreads();
    float Z = zp[t & 1][0] + zp[t & 1][1] + zp[t & 1][2] + zp[t & 1][3];
    float at = E * __builtin_amdgcn_rcpf(Z);
    lp += fminf(at, cov) * dms[t];
    cov += at;
    out_attn[(size_t)(b * Tq + t) * Sq + s] = at;
    cur = nxt;
  }

  out_covf[b * Sq + s] = cov;
  float wl = wave64_sum(lp);
  if (ln == 0) lred[w] = wl;
  __syncthreads();
  if (s == 0) atomicAdd(lacc, lred[0] + lred[1] + lred[2] + lred[3]);
}

// ---------------- deferred ht = attn @ enc + loss finalize --------------------
__global__ __launch_bounds__(256) void ht_kernel(
    const float* __restrict__ attn, const float* __restrict__ enc,
    const float* __restrict__ dmask, const float* __restrict__ lacc,
    float* __restrict__ out_ht, float* __restrict__ out_loss)
{
  __shared__ float lat[Sq][8];
  __shared__ float r4[4];
  int bid = blockIdx.x;
  int b = bid / 24, r = bid % 24, tc = r / 3, hc = r % 3;
  int tid = threadIdx.x;
  int h = hc * 256 + tid;
#pragma unroll
  for (int tt = 0; tt < 8; tt++)
    lat[tid][tt] = attn[(size_t)(b * Tq + tc * 8 + tt) * Sq + tid];
  __syncthreads();

  float acc[8] = {};
  const float* ep = enc + (size_t)(b * Sq) * Hq + h;
  for (int sb = 0; sb < Sq; sb += 8) {
    float e[8];
#pragma unroll
    for (int u = 0; u < 8; u++) e[u] = ep[(size_t)(sb + u) * Hq];
#pragma unroll
    for (int u = 0; u < 8; u++) {
      f32x4 a0 = *(const f32x4*)&lat[sb + u][0];
      f32x4 a1 = *(const f32x4*)&lat[sb + u][4];
      acc[0] += a0[0] * e[u]; acc[1] += a0[1] * e[u];
      acc[2] += a0[2] * e[u]; acc[3] += a0[3] * e[u];
      acc[4] += a1[0] * e[u]; acc[5] += a1[1] * e[u];
      acc[6] += a1[2] * e[u]; acc[7] += a1[3] * e[u];
    }
  }
#pragma unroll
  for (int tt = 0; tt < 8; tt++)
    out_ht[(size_t)(b * Tq + tc * 8 + tt) * Hq + h] = acc[tt];

  if (blockIdx.x == 0) {
    float s = 0.f;
    for (int i = tid; i < Bq * Tq; i += 256) s += dmask[i];
#pragma unroll
    for (int off = 32; off; off >>= 1) s += __shfl_xor(s, off);
    int w = tid >> 6, ln = tid & 63;
    if (ln == 0) r4[w] = s;
    __syncthreads();
    if (tid == 0) out_loss[0] = lacc[0] / (r4[0] + r4[1] + r4[2] + r4[3]);
  }
}

extern "C" void kernel_launch(void* const* d_in, const int* in_sizes, int n_in,
                              void* d_out, int out_size, void* d_ws, size_t ws_size,
                              hipStream_t stream) {
  const float* dec   = (const float*)d_in[0];   // [8,64,768]
  const float* dmask = (const float*)d_in[1];   // [8,64]
  const float* enc   = (const float*)d_in[2];   // [8,256,768]
  const float* emask = (const float*)d_in[3];   // [8,256]
  const float* cov0  = (const float*)d_in[4];   // [8,256]
  const float* Wh    = (const float*)d_in[5];   // [768,768]
  const float* Wd    = (const float*)d_in[6];   // [768,768]
  const float* bd    = (const float*)d_in[7];   // [768]
  const float* wc    = (const float*)d_in[8];   // [768]
  const float* vv    = (const float*)d_in[9];   // [768]
  float* out = (float*)d_out;

  char* ws = (char*)d_ws;
  __bf16* efh  = (__bf16*)ws;                    // 2048*768*2 = 3145728 B
  float*  decf = (float*)(ws + 3145728);         // 512*768*4 = 1572864 B
  f32x4*  abcd = (f32x4*)(ws + 4718592);         // 8*64*256*16 = 2097152 B
  float*  lacc = (float*)(ws + 6815744);         // 4 B

  const size_t OFF_ATTN = (size_t)Bq * Tq * Hq;             // 393216
  const size_t OFF_LOSS = OFF_ATTN + (size_t)Bq * Tq * Sq;  // 524288
  const size_t OFF_COV  = OFF_LOSS + 1;                     // 524289

  proj_kernel<<<480, 256, 0, stream>>>(enc, dec, Wh, Wd, bd, efh, decf, lacc);
  abcd_kernel<<<512, 256, 0, stream>>>(efh, decf, wc, vv, abcd);
  scan2_kernel<<<Bq, 256, 0, stream>>>(abcd, emask, cov0, dmask,
                                       out + OFF_ATTN, out + OFF_COV, lacc);
  ht_kernel<<<192, 256, 0, stream>>>(out + OFF_ATTN, enc, dmask, lacc,
                                     out, out + OFF_LOSS);
}

// Round 14
// 143.449 us; speedup vs baseline: 1.4770x; 1.1288x over previous
//
#include <hip/hip_runtime.h>

#define Bq 8
#define Tq 64
#define Sq 256
#define Hq 768

typedef float f32x4 __attribute__((ext_vector_type(4)));
typedef __bf16 bf16x8 __attribute__((ext_vector_type(8)));

#define TANH_SCALE 2.885390081777927f   // 2*log2(e): exp2(u*TS) = e^{2u}
#define LOG2E 1.4426950408889634f

// ---- DPP wave reduction -----------------------------------------------------
template <int Ctrl, int Rmask>
__device__ __forceinline__ float dpp_add_f(float v) {
  int t = __builtin_amdgcn_update_dpp(0, __float_as_int(v), Ctrl, Rmask, 0xF, true);
  return v + __int_as_float(t);
}
__device__ __forceinline__ float wave64_sum(float v) {
  v = dpp_add_f<0xB1, 0xF>(v);
  v = dpp_add_f<0x4E, 0xF>(v);
  v = dpp_add_f<0x141, 0xF>(v);
  v = dpp_add_f<0x140, 0xF>(v);
  v = dpp_add_f<0x142, 0xA>(v);
  v = dpp_add_f<0x143, 0xC>(v);
  return __int_as_float(__builtin_amdgcn_readlane(__float_as_int(v), 63));
}

// ---------------- projection GEMMs (bf16 MFMA) --------------------------------
// Both outputs stored bf16 (TS-scaled; dec gets +bias first).
__global__ __launch_bounds__(256) void proj_kernel(
    const float* __restrict__ enc, const float* __restrict__ dec,
    const float* __restrict__ Wh, const float* __restrict__ Wd,
    const float* __restrict__ bd,
    __bf16* __restrict__ efh, __bf16* __restrict__ decfh,
    float* __restrict__ lacc)
{
  if (blockIdx.x == 0 && threadIdx.x == 0) lacc[0] = 0.f;

  int bid = blockIdx.x;
  const int efBlocks = 384;
  const float* A; const float* W; bool isEf;
  int bm, bn;
  if (bid < efBlocks) {
    A = enc; W = Wh; isEf = true;
    bm = bid % 32; bn = bid / 32;               // XCD affinity
  } else {
    bid -= efBlocks;
    A = dec; W = Wd; isEf = false;
    bm = bid % 8; bn = bid / 8;
  }
  int w = threadIdx.x >> 6, ln = threadIdx.x & 63;
  int m0 = bm * 64 + (w >> 1) * 32;
  int n0 = bn * 64 + (w & 1) * 32;
  int rsel = ln & 15;
  int kof = (ln >> 4) * 8;
  f32x4 acc[2][2] = {};
  for (int k0 = 0; k0 < Hq; k0 += 32) {
    bf16x8 af[2], bfr[2];
#pragma unroll
    for (int tm = 0; tm < 2; tm++) {
      const float* p = A + (size_t)(m0 + tm * 16 + rsel) * Hq + k0 + kof;
      f32x4 lo = *(const f32x4*)p, hi = *(const f32x4*)(p + 4);
      bf16x8 t;
      t[0] = (__bf16)lo[0]; t[1] = (__bf16)lo[1]; t[2] = (__bf16)lo[2]; t[3] = (__bf16)lo[3];
      t[4] = (__bf16)hi[0]; t[5] = (__bf16)hi[1]; t[6] = (__bf16)hi[2]; t[7] = (__bf16)hi[3];
      af[tm] = t;
    }
#pragma unroll
    for (int tn = 0; tn < 2; tn++) {
      const float* p = W + (size_t)(n0 + tn * 16 + rsel) * Hq + k0 + kof;
      f32x4 lo = *(const f32x4*)p, hi = *(const f32x4*)(p + 4);
      bf16x8 t;
      t[0] = (__bf16)lo[0]; t[1] = (__bf16)lo[1]; t[2] = (__bf16)lo[2]; t[3] = (__bf16)lo[3];
      t[4] = (__bf16)hi[0]; t[5] = (__bf16)hi[1]; t[6] = (__bf16)hi[2]; t[7] = (__bf16)hi[3];
      bfr[tn] = t;
    }
#pragma unroll
    for (int tm = 0; tm < 2; tm++)
#pragma unroll
      for (int tn = 0; tn < 2; tn++)
        acc[tm][tn] = __builtin_amdgcn_mfma_f32_16x16x32_bf16(af[tm], bfr[tn], acc[tm][tn], 0, 0, 0);
  }
  int col = ln & 15, rb = (ln >> 4) * 4;
#pragma unroll
  for (int tm = 0; tm < 2; tm++)
#pragma unroll
    for (int tn = 0; tn < 2; tn++)
#pragma unroll
      for (int j = 0; j < 4; j++) {
        int r = m0 + tm * 16 + rb + j, c = n0 + tn * 16 + col;
        float val = acc[tm][tn][j];
        if (isEf) {
          efh[(size_t)r * Hq + c] = (__bf16)(val * TANH_SCALE);
        } else {
          decfh[(size_t)r * Hq + c] = (__bf16)((val + bd[c]) * TANH_SCALE);
        }
      }
}

// ---------------- ABC precompute ----------------------------------------------
// score_s(t; cov) ~= A + cov*B + cov^2*C. 1024 blocks = 8b x 8tt x 16st;
// 256 threads = 128 (t,s) pairs x 2 h-halves. Vector LDS reads, prestaged
// {v, v*wc, v*wc^2}. efs pad 780 shorts: 8B-aligned rows, conflict-free.
#define TT 8
#define ST 16
__global__ __launch_bounds__(256, 3) void abcd_kernel(
    const __bf16* __restrict__ efh, const __bf16* __restrict__ decfh,
    const float* __restrict__ wcvec, const float* __restrict__ vvec,
    f32x4* __restrict__ abcd)
{
  __shared__ unsigned short efs[ST][780];   // bf16 bits
  __shared__ unsigned short dts[TT][768];   // bf16 bits (broadcast reads)
  __shared__ float vvs[768], vwcs[768], vw2s[768];
  __shared__ float part[128][4];
  const int b = blockIdx.x & 7;
  const int r = blockIdx.x >> 3;            // 0..127
  const int tt0 = (r & 7) * TT;
  const int st0 = (r >> 3) * ST;
  const int tid = threadIdx.x;

  // stage ef tile: 16 rows x 192 uint2-groups (4 bf16 each)
  for (int i = tid; i < ST * 192; i += 256) {
    int row = i / 192, c = (i % 192) * 4;
    *(uint2*)&efs[row][c] =
        *(const uint2*)(efh + (size_t)(b * Sq + st0 + row) * Hq + c);
  }
  for (int i = tid; i < TT * 192; i += 256) {
    int row = i / 192, c = (i % 192) * 4;
    *(uint2*)&dts[row][c] =
        *(const uint2*)(decfh + (size_t)(b * Tq + tt0 + row) * Hq + c);
  }
  for (int i = tid; i < 768; i += 256) {
    float wc = wcvec[i], v = vvec[i];
    vvs[i] = v; vwcs[i] = v * wc; vw2s[i] = v * wc * wc;
  }
  __syncthreads();

  const int hh = tid >> 7;                  // 0/1: h-half
  const int pid = tid & 127;
  const int tl = pid >> 4, sl = pid & 15;
  const int hbase = hh * 384;

  float A = 0.f, B = 0.f, Cp = 0.f;
#define BLO(x) __uint_as_float((x) << 16)
#define BHI(x) __uint_as_float((x) & 0xFFFF0000u)
#pragma unroll 2
  for (int j = 0; j < 384; j += 4) {
    uint2 eu = *(const uint2*)&efs[sl][hbase + j];
    uint2 du = *(const uint2*)&dts[tl][hbase + j];
    f32x4 v4 = *(const f32x4*)&vvs[hbase + j];
    f32x4 w1 = *(const f32x4*)&vwcs[hbase + j];
    f32x4 w2 = *(const f32x4*)&vw2s[hbase + j];
    float u[4];
    u[0] = BLO(eu.x) + BLO(du.x);
    u[1] = BHI(eu.x) + BHI(du.x);
    u[2] = BLO(eu.y) + BLO(du.y);
    u[3] = BHI(eu.y) + BHI(du.y);
#pragma unroll
    for (int e = 0; e < 4; e++) {
      float e2 = __builtin_amdgcn_exp2f(u[e]);
      float rr = __builtin_amdgcn_rcpf(1.f + e2);
      float t0 = 1.f - 2.f * rr;
      float f1 = 1.f - t0 * t0;
      A  += v4[e] * t0;
      B  += w1[e] * f1;
      Cp += w2[e] * (t0 * f1);
    }
  }
#undef BLO
#undef BHI

  if (hh == 1) {
    part[pid][0] = A; part[pid][1] = B; part[pid][2] = Cp;
  }
  __syncthreads();
  if (hh == 0) {
    f32x4 outv;
    outv[0] = A + part[pid][0];
    outv[1] = B + part[pid][1];
    outv[2] = -(Cp + part[pid][2]);
    outv[3] = 0.f;
    abcd[(size_t)(b * Tq + tt0 + tl) * Sq + st0 + sl] = outv;
  }
}

// ---------------- scan: one batch = one 256-thread block ----------------------
__global__ __launch_bounds__(256, 1) void scan2_kernel(
    const f32x4* __restrict__ abcd, const float* __restrict__ emask,
    const float* __restrict__ cov0, const float* __restrict__ dmask,
    float* __restrict__ out_attn, float* __restrict__ out_covf,
    float* __restrict__ lacc)
{
  __shared__ float zp[2][4];
  __shared__ float dms[Tq];
  __shared__ float lred[4];
  const int b = blockIdx.x;
  const int s = threadIdx.x;
  const int w = s >> 6, ln = s & 63;
  if (s < Tq) dms[s] = dmask[b * Tq + s];
  const float em = emask[b * Sq + s];
  float cov = cov0[b * Sq + s];
  float lp = 0.f;
  const f32x4* P = abcd + (size_t)b * Tq * Sq + s;
  f32x4 cur = P[0];
  __syncthreads();

  for (int t = 0; t < Tq; t++) {
    f32x4 nxt = (t + 1 < Tq) ? P[(size_t)(t + 1) * Sq] : cur;  // prefetch
    float sc = cur[0] + cov * (cur[1] + cov * (cur[2] + cov * cur[3]));
    float E = __builtin_amdgcn_exp2f(sc * LOG2E) * em;
    float wsum = wave64_sum(E);
    if (ln == 0) zp[t & 1][w] = wsum;
    __syncthreads();
    float Z = zp[t & 1][0] + zp[t & 1][1] + zp[t & 1][2] + zp[t & 1][3];
    float at = E * __builtin_amdgcn_rcpf(Z);
    lp += fminf(at, cov) * dms[t];
    cov += at;
    out_attn[(size_t)(b * Tq + t) * Sq + s] = at;
    cur = nxt;
  }

  out_covf[b * Sq + s] = cov;
  float wl = wave64_sum(lp);
  if (ln == 0) lred[w] = wl;
  __syncthreads();
  if (s == 0) atomicAdd(lacc, lred[0] + lred[1] + lred[2] + lred[3]);
}

// ---------------- deferred ht = attn @ enc + loss finalize --------------------
__global__ __launch_bounds__(256) void ht_kernel(
    const float* __restrict__ attn, const float* __restrict__ enc,
    const float* __restrict__ dmask, const float* __restrict__ lacc,
    float* __restrict__ out_ht, float* __restrict__ out_loss)
{
  __shared__ float lat[Sq][8];
  __shared__ float r4[4];
  int bid = blockIdx.x;
  int b = bid / 24, r = bid % 24, tc = r / 3, hc = r % 3;
  int tid = threadIdx.x;
  int h = hc * 256 + tid;
#pragma unroll
  for (int tt = 0; tt < 8; tt++)
    lat[tid][tt] = attn[(size_t)(b * Tq + tc * 8 + tt) * Sq + tid];
  __syncthreads();

  float acc[8] = {};
  const float* ep = enc + (size_t)(b * Sq) * Hq + h;
  for (int sb = 0; sb < Sq; sb += 8) {
    float e[8];
#pragma unroll
    for (int u = 0; u < 8; u++) e[u] = ep[(size_t)(sb + u) * Hq];
#pragma unroll
    for (int u = 0; u < 8; u++) {
      f32x4 a0 = *(const f32x4*)&lat[sb + u][0];
      f32x4 a1 = *(const f32x4*)&lat[sb + u][4];
      acc[0] += a0[0] * e[u]; acc[1] += a0[1] * e[u];
      acc[2] += a0[2] * e[u]; acc[3] += a0[3] * e[u];
      acc[4] += a1[0] * e[u]; acc[5] += a1[1] * e[u];
      acc[6] += a1[2] * e[u]; acc[7] += a1[3] * e[u];
    }
  }
#pragma unroll
  for (int tt = 0; tt < 8; tt++)
    out_ht[(size_t)(b * Tq + tc * 8 + tt) * Hq + h] = acc[tt];

  if (blockIdx.x == 0) {
    float s = 0.f;
    for (int i = tid; i < Bq * Tq; i += 256) s += dmask[i];
#pragma unroll
    for (int off = 32; off; off >>= 1) s += __shfl_xor(s, off);
    int w = tid >> 6, ln = tid & 63;
    if (ln == 0) r4[w] = s;
    __syncthreads();
    if (tid == 0) out_loss[0] = lacc[0] / (r4[0] + r4[1] + r4[2] + r4[3]);
  }
}

extern "C" void kernel_launch(void* const* d_in, const int* in_sizes, int n_in,
                              void* d_out, int out_size, void* d_ws, size_t ws_size,
                              hipStream_t stream) {
  const float* dec   = (const float*)d_in[0];   // [8,64,768]
  const float* dmask = (const float*)d_in[1];   // [8,64]
  const float* enc   = (const float*)d_in[2];   // [8,256,768]
  const float* emask = (const float*)d_in[3];   // [8,256]
  const float* cov0  = (const float*)d_in[4];   // [8,256]
  const float* Wh    = (const float*)d_in[5];   // [768,768]
  const float* Wd    = (const float*)d_in[6];   // [768,768]
  const float* bd    = (const float*)d_in[7];   // [768]
  const float* wc    = (const float*)d_in[8];   // [768]
  const float* vv    = (const float*)d_in[9];   // [768]
  float* out = (float*)d_out;

  char* ws = (char*)d_ws;
  __bf16* efh   = (__bf16*)ws;                   // 2048*768*2 = 3145728 B
  __bf16* decfh = (__bf16*)(ws + 3145728);       // 512*768*2 = 786432 B
  f32x4*  abcd  = (f32x4*)(ws + 3932160);        // 8*64*256*16 = 2097152 B
  float*  lacc  = (float*)(ws + 6029312);        // 4 B

  const size_t OFF_ATTN = (size_t)Bq * Tq * Hq;             // 393216
  const size_t OFF_LOSS = OFF_ATTN + (size_t)Bq * Tq * Sq;  // 524288
  const size_t OFF_COV  = OFF_LOSS + 1;                     // 524289

  proj_kernel<<<480, 256, 0, stream>>>(enc, dec, Wh, Wd, bd, efh, decfh, lacc);
  abcd_kernel<<<1024, 256, 0, stream>>>(efh, decfh, wc, vv, abcd);
  scan2_kernel<<<Bq, 256, 0, stream>>>(abcd, emask, cov0, dmask,
                                       out + OFF_ATTN, out + OFF_COV, lacc);
  ht_kernel<<<192, 256, 0, stream>>>(out + OFF_ATTN, enc, dmask, lacc,
                                     out, out + OFF_LOSS);
}

// Round 15
// 135.221 us; speedup vs baseline: 1.5669x; 1.0608x over previous
//
#include <hip/hip_runtime.h>

#define Bq 8
#define Tq 64
#define Sq 256
#define Hq 768

typedef float f32x4 __attribute__((ext_vector_type(4)));
typedef __bf16 bf16x8 __attribute__((ext_vector_type(8)));

#define TANH_SCALE 2.885390081777927f   // 2*log2(e): exp2(u*TS) = e^{2u}
#define LOG2E 1.4426950408889634f

// ---- DPP wave reduction -----------------------------------------------------
template <int Ctrl, int Rmask>
__device__ __forceinline__ float dpp_add_f(float v) {
  int t = __builtin_amdgcn_update_dpp(0, __float_as_int(v), Ctrl, Rmask, 0xF, true);
  return v + __int_as_float(t);
}
__device__ __forceinline__ float wave64_sum(float v) {
  v = dpp_add_f<0xB1, 0xF>(v);
  v = dpp_add_f<0x4E, 0xF>(v);
  v = dpp_add_f<0x141, 0xF>(v);
  v = dpp_add_f<0x140, 0xF>(v);
  v = dpp_add_f<0x142, 0xA>(v);
  v = dpp_add_f<0x143, 0xC>(v);
  return __int_as_float(__builtin_amdgcn_readlane(__float_as_int(v), 63));
}

// ---------------- projection GEMMs (bf16 MFMA) --------------------------------
// Side duty: precompute w1=v*wc, w2=v*wc^2 streams + zero lacc.
__global__ __launch_bounds__(256) void proj_kernel(
    const float* __restrict__ enc, const float* __restrict__ dec,
    const float* __restrict__ Wh, const float* __restrict__ Wd,
    const float* __restrict__ bd,
    const float* __restrict__ wcvec, const float* __restrict__ vvec,
    __bf16* __restrict__ efh, __bf16* __restrict__ decfh,
    float* __restrict__ w1g, float* __restrict__ w2g,
    float* __restrict__ lacc)
{
  {
    int gidx = blockIdx.x * 256 + threadIdx.x;
    if (gidx < Hq) {
      float v = vvec[gidx], wc = wcvec[gidx];
      w1g[gidx] = v * wc;
      w2g[gidx] = v * wc * wc;
    }
    if (gidx == 0) lacc[0] = 0.f;
  }

  int bid = blockIdx.x;
  const int efBlocks = 384;
  const float* A; const float* W; bool isEf;
  int bm, bn;
  if (bid < efBlocks) {
    A = enc; W = Wh; isEf = true;
    bm = bid % 32; bn = bid / 32;               // XCD affinity
  } else {
    bid -= efBlocks;
    A = dec; W = Wd; isEf = false;
    bm = bid % 8; bn = bid / 8;
  }
  int w = threadIdx.x >> 6, ln = threadIdx.x & 63;
  int m0 = bm * 64 + (w >> 1) * 32;
  int n0 = bn * 64 + (w & 1) * 32;
  int rsel = ln & 15;
  int kof = (ln >> 4) * 8;
  f32x4 acc[2][2] = {};
  for (int k0 = 0; k0 < Hq; k0 += 32) {
    bf16x8 af[2], bfr[2];
#pragma unroll
    for (int tm = 0; tm < 2; tm++) {
      const float* p = A + (size_t)(m0 + tm * 16 + rsel) * Hq + k0 + kof;
      f32x4 lo = *(const f32x4*)p, hi = *(const f32x4*)(p + 4);
      bf16x8 t;
      t[0] = (__bf16)lo[0]; t[1] = (__bf16)lo[1]; t[2] = (__bf16)lo[2]; t[3] = (__bf16)lo[3];
      t[4] = (__bf16)hi[0]; t[5] = (__bf16)hi[1]; t[6] = (__bf16)hi[2]; t[7] = (__bf16)hi[3];
      af[tm] = t;
    }
#pragma unroll
    for (int tn = 0; tn < 2; tn++) {
      const float* p = W + (size_t)(n0 + tn * 16 + rsel) * Hq + k0 + kof;
      f32x4 lo = *(const f32x4*)p, hi = *(const f32x4*)(p + 4);
      bf16x8 t;
      t[0] = (__bf16)lo[0]; t[1] = (__bf16)lo[1]; t[2] = (__bf16)lo[2]; t[3] = (__bf16)lo[3];
      t[4] = (__bf16)hi[0]; t[5] = (__bf16)hi[1]; t[6] = (__bf16)hi[2]; t[7] = (__bf16)hi[3];
      bfr[tn] = t;
    }
#pragma unroll
    for (int tm = 0; tm < 2; tm++)
#pragma unroll
      for (int tn = 0; tn < 2; tn++)
        acc[tm][tn] = __builtin_amdgcn_mfma_f32_16x16x32_bf16(af[tm], bfr[tn], acc[tm][tn], 0, 0, 0);
  }
  int col = ln & 15, rb = (ln >> 4) * 4;
#pragma unroll
  for (int tm = 0; tm < 2; tm++)
#pragma unroll
    for (int tn = 0; tn < 2; tn++)
#pragma unroll
      for (int j = 0; j < 4; j++) {
        int r = m0 + tm * 16 + rb + j, c = n0 + tn * 16 + col;
        float val = acc[tm][tn][j];
        if (isEf) {
          efh[(size_t)r * Hq + c] = (__bf16)(val * TANH_SCALE);
        } else {
          decfh[(size_t)r * Hq + c] = (__bf16)((val + bd[c]) * TANH_SCALE);
        }
      }
}

// ---------------- ABC precompute ----------------------------------------------
// score_s(t; cov) ~= A + cov*B + cov^2*C. 1024 blocks = 8b x 8tt x 16st;
// 256 threads = 128 (t,s) pairs x 2 h-halves. ef/dec tiles in LDS (bf16,
// conflict-free pads 780/776); v/w1/w2 via wave-uniform scalar loads.
#define TT 8
#define ST 16
__global__ __launch_bounds__(256, 4) void abcd_kernel(
    const __bf16* __restrict__ efh, const __bf16* __restrict__ decfh,
    const float* __restrict__ vvec, const float* __restrict__ w1g,
    const float* __restrict__ w2g,
    f32x4* __restrict__ abcd)
{
  __shared__ unsigned short efs[ST][780];   // 388.5 dw stride -> banks 6k
  __shared__ unsigned short dts[TT][776];   // 388 dw stride -> banks 4k
  __shared__ float part[128][4];
  const int b = blockIdx.x & 7;
  const int r = blockIdx.x >> 3;            // 0..127
  const int tt0 = (r & 7) * TT;
  const int st0 = (r >> 3) * ST;
  const int tid = threadIdx.x;

  for (int i = tid; i < ST * 192; i += 256) {
    int row = i / 192, c = (i % 192) * 4;
    *(uint2*)&efs[row][c] =
        *(const uint2*)(efh + (size_t)(b * Sq + st0 + row) * Hq + c);
  }
  for (int i = tid; i < TT * 192; i += 256) {
    int row = i / 192, c = (i % 192) * 4;
    *(uint2*)&dts[row][c] =
        *(const uint2*)(decfh + (size_t)(b * Tq + tt0 + row) * Hq + c);
  }
  __syncthreads();

  const int hh = tid >> 7;                  // 0/1: h-half
  const int pid = tid & 127;
  const int tl = pid >> 4, sl = pid & 15;
  const int hbase = hh * 384;
  // wave-uniform bases -> scalar (s_load) path for the coefficient streams
  const int hbu = __builtin_amdgcn_readfirstlane(hbase);
  const float* vp  = vvec + hbu;
  const float* w1p = w1g + hbu;
  const float* w2p = w2g + hbu;

  float A = 0.f, B = 0.f, Cp = 0.f;
#define BLO(x) __uint_as_float((x) << 16)
#define BHI(x) __uint_as_float((x) & 0xFFFF0000u)
#pragma unroll 4
  for (int j = 0; j < 384; j += 4) {
    uint2 eu = *(const uint2*)&efs[sl][hbase + j];
    uint2 du = *(const uint2*)&dts[tl][hbase + j];
    f32x4 v4 = *(const f32x4*)(vp + j);
    f32x4 w1 = *(const f32x4*)(w1p + j);
    f32x4 w2 = *(const f32x4*)(w2p + j);
    float u[4];
    u[0] = BLO(eu.x) + BLO(du.x);
    u[1] = BHI(eu.x) + BHI(du.x);
    u[2] = BLO(eu.y) + BLO(du.y);
    u[3] = BHI(eu.y) + BHI(du.y);
#pragma unroll
    for (int e = 0; e < 4; e++) {
      float e2 = __builtin_amdgcn_exp2f(u[e]);
      float rr = __builtin_amdgcn_rcpf(1.f + e2);
      float t0 = 1.f - 2.f * rr;
      float f1 = 1.f - t0 * t0;
      A  += v4[e] * t0;
      B  += w1[e] * f1;
      Cp += w2[e] * (t0 * f1);
    }
  }
#undef BLO
#undef BHI

  if (hh == 1) {
    part[pid][0] = A; part[pid][1] = B; part[pid][2] = Cp;
  }
  __syncthreads();
  if (hh == 0) {
    f32x4 outv;
    outv[0] = A + part[pid][0];
    outv[1] = B + part[pid][1];
    outv[2] = -(Cp + part[pid][2]);
    outv[3] = 0.f;
    abcd[(size_t)(b * Tq + tt0 + tl) * Sq + st0 + sl] = outv;
  }
}

// ---------------- scan: one batch = one 256-thread block ----------------------
__global__ __launch_bounds__(256, 1) void scan2_kernel(
    const f32x4* __restrict__ abcd, const float* __restrict__ emask,
    const float* __restrict__ cov0, const float* __restrict__ dmask,
    float* __restrict__ out_attn, float* __restrict__ out_covf,
    float* __restrict__ lacc)
{
  __shared__ float zp[2][4];
  __shared__ float dms[Tq];
  __shared__ float lred[4];
  const int b = blockIdx.x;
  const int s = threadIdx.x;
  const int w = s >> 6, ln = s & 63;
  if (s < Tq) dms[s] = dmask[b * Tq + s];
  const float em = emask[b * Sq + s];
  float cov = cov0[b * Sq + s];
  float lp = 0.f;
  const f32x4* P = abcd + (size_t)b * Tq * Sq + s;
  f32x4 cur = P[0];
  __syncthreads();

  for (int t = 0; t < Tq; t++) {
    f32x4 nxt = (t + 1 < Tq) ? P[(size_t)(t + 1) * Sq] : cur;  // prefetch
    float sc = cur[0] + cov * (cur[1] + cov * (cur[2] + cov * cur[3]));
    float E = __builtin_amdgcn_exp2f(sc * LOG2E) * em;
    float wsum = wave64_sum(E);
    if (ln == 0) zp[t & 1][w] = wsum;
    __syncthreads();
    float Z = zp[t & 1][0] + zp[t & 1][1] + zp[t & 1][2] + zp[t & 1][3];
    float at = E * __builtin_amdgcn_rcpf(Z);
    lp += fminf(at, cov) * dms[t];
    cov += at;
    out_attn[(size_t)(b * Tq + t) * Sq + s] = at;
    cur = nxt;
  }

  out_covf[b * Sq + s] = cov;
  float wl = wave64_sum(lp);
  if (ln == 0) lred[w] = wl;
  __syncthreads();
  if (s == 0) atomicAdd(lacc, lred[0] + lred[1] + lred[2] + lred[3]);
}

// ---------------- deferred ht = attn @ enc + loss finalize --------------------
__global__ __launch_bounds__(256) void ht_kernel(
    const float* __restrict__ attn, const float* __restrict__ enc,
    const float* __restrict__ dmask, const float* __restrict__ lacc,
    float* __restrict__ out_ht, float* __restrict__ out_loss)
{
  __shared__ float lat[Sq][8];
  __shared__ float r4[4];
  int bid = blockIdx.x;
  int b = bid / 24, r = bid % 24, tc = r / 3, hc = r % 3;
  int tid = threadIdx.x;
  int h = hc * 256 + tid;
#pragma unroll
  for (int tt = 0; tt < 8; tt++)
    lat[tid][tt] = attn[(size_t)(b * Tq + tc * 8 + tt) * Sq + tid];
  __syncthreads();

  float acc[8] = {};
  const float* ep = enc + (size_t)(b * Sq) * Hq + h;
  for (int sb = 0; sb < Sq; sb += 8) {
    float e[8];
#pragma unroll
    for (int u = 0; u < 8; u++) e[u] = ep[(size_t)(sb + u) * Hq];
#pragma unroll
    for (int u = 0; u < 8; u++) {
      f32x4 a0 = *(const f32x4*)&lat[sb + u][0];
      f32x4 a1 = *(const f32x4*)&lat[sb + u][4];
      acc[0] += a0[0] * e[u]; acc[1] += a0[1] * e[u];
      acc[2] += a0[2] * e[u]; acc[3] += a0[3] * e[u];
      acc[4] += a1[0] * e[u]; acc[5] += a1[1] * e[u];
      acc[6] += a1[2] * e[u]; acc[7] += a1[3] * e[u];
    }
  }
#pragma unroll
  for (int tt = 0; tt < 8; tt++)
    out_ht[(size_t)(b * Tq + tc * 8 + tt) * Hq + h] = acc[tt];

  if (blockIdx.x == 0) {
    float s = 0.f;
    for (int i = tid; i < Bq * Tq; i += 256) s += dmask[i];
#pragma unroll
    for (int off = 32; off; off >>= 1) s += __shfl_xor(s, off);
    int w = tid >> 6, ln = tid & 63;
    if (ln == 0) r4[w] = s;
    __syncthreads();
    if (tid == 0) out_loss[0] = lacc[0] / (r4[0] + r4[1] + r4[2] + r4[3]);
  }
}

extern "C" void kernel_launch(void* const* d_in, const int* in_sizes, int n_in,
                              void* d_out, int out_size, void* d_ws, size_t ws_size,
                              hipStream_t stream) {
  const float* dec   = (const float*)d_in[0];   // [8,64,768]
  const float* dmask = (const float*)d_in[1];   // [8,64]
  const float* enc   = (const float*)d_in[2];   // [8,256,768]
  const float* emask = (const float*)d_in[3];   // [8,256]
  const float* cov0  = (const float*)d_in[4];   // [8,256]
  const float* Wh    = (const float*)d_in[5];   // [768,768]
  const float* Wd    = (const float*)d_in[6];   // [768,768]
  const float* bd    = (const float*)d_in[7];   // [768]
  const float* wc    = (const float*)d_in[8];   // [768]
  const float* vv    = (const float*)d_in[9];   // [768]
  float* out = (float*)d_out;

  char* ws = (char*)d_ws;
  __bf16* efh   = (__bf16*)ws;                   // 3145728 B
  __bf16* decfh = (__bf16*)(ws + 3145728);       // 786432 B
  f32x4*  abcd  = (f32x4*)(ws + 3932160);        // 2097152 B
  float*  w1g   = (float*)(ws + 6029312);        // 3072 B
  float*  w2g   = (float*)(ws + 6032384);        // 3072 B
  float*  lacc  = (float*)(ws + 6035456);        // 4 B

  const size_t OFF_ATTN = (size_t)Bq * Tq * Hq;             // 393216
  const size_t OFF_LOSS = OFF_ATTN + (size_t)Bq * Tq * Sq;  // 524288
  const size_t OFF_COV  = OFF_LOSS + 1;                     // 524289

  proj_kernel<<<480, 256, 0, stream>>>(enc, dec, Wh, Wd, bd, wc, vv,
                                       efh, decfh, w1g, w2g, lacc);
  abcd_kernel<<<1024, 256, 0, stream>>>(efh, decfh, vv, w1g, w2g, abcd);
  scan2_kernel<<<Bq, 256, 0, stream>>>(abcd, emask, cov0, dmask,
                                       out + OFF_ATTN, out + OFF_COV, lacc);
  ht_kernel<<<192, 256, 0, stream>>>(out + OFF_ATTN, enc, dmask, lacc,
                                     out, out + OFF_LOSS);
}